// Round 3
// baseline (228.326 us; speedup 1.0000x reference)
//
#include <hip/hip_runtime.h>

typedef unsigned short u16;
typedef __attribute__((ext_vector_type(8))) __bf16 bf16x8;
typedef __attribute__((ext_vector_type(4))) float f32x4;
typedef __attribute__((ext_vector_type(4))) unsigned int u32x4;

#define MFMA16(a, b, c) __builtin_amdgcn_mfma_f32_16x16x32_bf16(a, b, c, 0, 0, 0)

__device__ __forceinline__ u16 f2bf(float f) {
    unsigned u = __float_as_uint(f);
    u = (u + 0x7FFFu + ((u >> 16) & 1u)) >> 16;
    return (u16)u;
}

// async global->LDS, 16B per lane; LDS dest = wave-uniform base + lane*16
__device__ __forceinline__ void gl_lds16(const u16* g, u16* l) {
    __builtin_amdgcn_global_load_lds(
        (const __attribute__((address_space(1))) unsigned int*)g,
        (__attribute__((address_space(3))) unsigned int*)l, 16, 0, 0);
}

static constexpr int Bv = 2, Tv = 2048, Cv = 1024, Hv = 16, Dv = 64;
static constexpr int Mv = Bv * Tv; // 4096

// ws element offsets (u16 elements)
static constexpr size_t OFF_XB = 0;                      // x bf16       [4096,1024]
static constexpr size_t OFF_WQ = 4194304;                // Wq bf16      [1024,1024]
static constexpr size_t OFF_WK = OFF_WQ + 1048576;
static constexpr size_t OFF_WV = OFF_WK + 1048576;
static constexpr size_t OFF_WO = OFF_WV + 1048576;
static constexpr size_t OFF_Q  = OFF_WO + 1048576;       // Q bf16 [M, C]
static constexpr size_t OFF_K  = OFF_Q + 4194304;        // K bf16 [M, C]
static constexpr size_t OFF_V  = OFF_K + 4194304;        // V^T bf16 [C, M]: [(h*64+d)][b*2048+t]
static constexpr size_t OFF_A  = OFF_V + 4194304;        // attended bf16 [M, C]

// ---------------- fp32 -> bf16 convert (x + 4 weights) ----------------
__global__ __launch_bounds__(256) void convert_all(
    const float* __restrict__ x,
    const float* __restrict__ wq, const float* __restrict__ wk,
    const float* __restrict__ wv, const float* __restrict__ wo,
    u16* __restrict__ dst)
{
    int i4 = blockIdx.x * blockDim.x + threadIdx.x;
    if (i4 >= 2097152) return;
    int idx = i4 * 4;
    const float* src; int off;
    if (idx < 4194304) { src = x; off = idx; }
    else {
        int rel = idx - 4194304;
        int j = rel >> 20;
        off = rel & 1048575;
        src = (j == 0) ? wq : (j == 1) ? wk : (j == 2) ? wv : wo;
    }
    float4 v = *(const float4*)(src + off);
    ushort4 o;
    o.x = f2bf(v.x); o.y = f2bf(v.y); o.z = f2bf(v.z); o.w = f2bf(v.w);
    *(ushort4*)(dst + idx) = o;
}

// ---------------- 128x128-tile bf16 GEMM body (m97 structure) ----------------
// out[M,N] = A[M,K] * W[N,K]^T + bias. 4 waves in 2x2, each 64x64.
// TRANS: write out transposed as out[col][Mv + row] (u16), for V^T.
template <bool OUT_BF16, bool TRANS>
__device__ __forceinline__ void gemm128_body(
    const u16* __restrict__ A, const u16* __restrict__ Wt,
    const float* __restrict__ bias, void* __restrict__ outp,
    int m0, int n0, int N, int K)
{
    __shared__ u16 lA[128 * 32];
    __shared__ u16 lB[128 * 32];
    const int tid  = threadIdx.x;
    const int lane = tid & 63, w = tid >> 6;
    const int quad = lane >> 4, lm = lane & 15;
    const int wm = (w & 1) * 64, wn = (w >> 1) * 64;

    f32x4 zero = {0.f, 0.f, 0.f, 0.f};
    f32x4 acc[4][4];
    #pragma unroll
    for (int mt = 0; mt < 4; mt++)
        #pragma unroll
        for (int nt = 0; nt < 4; nt++) acc[mt][nt] = zero;

    const int srow = lane >> 2, sseg = lane & 3;
    const u16* ga0 = A  + (size_t)(m0 + w * 16 + srow) * K + sseg * 8;
    const u16* ga1 = ga0 + (size_t)64 * K;
    const u16* gb0 = Wt + (size_t)(n0 + w * 16 + srow) * K + sseg * 8;
    const u16* gb1 = gb0 + (size_t)64 * K;
    u16* la0 = &lA[(w * 16) * 32];      u16* la1 = &lA[(64 + w * 16) * 32];
    u16* lb0 = &lB[(w * 16) * 32];      u16* lb1 = &lB[(64 + w * 16) * 32];

    for (int k0 = 0; k0 < K; k0 += 32) {
        gl_lds16(ga0 + k0, la0);
        gl_lds16(ga1 + k0, la1);
        gl_lds16(gb0 + k0, lb0);
        gl_lds16(gb1 + k0, lb1);
        __syncthreads();
        bf16x8 af[4], bf[4];
        #pragma unroll
        for (int mt = 0; mt < 4; mt++)
            af[mt] = *(const bf16x8*)&lA[(wm + mt * 16 + lm) * 32 + quad * 8];
        #pragma unroll
        for (int nt = 0; nt < 4; nt++)
            bf[nt] = *(const bf16x8*)&lB[(wn + nt * 16 + lm) * 32 + quad * 8];
        #pragma unroll
        for (int mt = 0; mt < 4; mt++)
            #pragma unroll
            for (int nt = 0; nt < 4; nt++)
                acc[mt][nt] = MFMA16(af[mt], bf[nt], acc[mt][nt]);
        __syncthreads();
    }

    #pragma unroll
    for (int nt = 0; nt < 4; nt++) {
        int col = n0 + wn + nt * 16 + lm;
        float bv = bias[col];
        #pragma unroll
        for (int mt = 0; mt < 4; mt++) {
            if (TRANS) {
                int row0 = m0 + wm + mt * 16 + quad * 4;
                ushort4 o;
                o.x = f2bf(acc[mt][nt][0] + bv);
                o.y = f2bf(acc[mt][nt][1] + bv);
                o.z = f2bf(acc[mt][nt][2] + bv);
                o.w = f2bf(acc[mt][nt][3] + bv);
                *(ushort4*)((u16*)outp + (size_t)col * Mv + row0) = o;
            } else {
                #pragma unroll
                for (int r = 0; r < 4; r++) {
                    int row = m0 + wm + mt * 16 + quad * 4 + r;
                    float v = acc[mt][nt][r] + bv;
                    if (OUT_BF16) ((u16*)outp)[(size_t)row * N + col] = f2bf(v);
                    else          ((float*)outp)[(size_t)row * N + col] = v;
                }
            }
        }
    }
}

// fused QKV: grid (24, 32); x in [0,8) -> Q, [8,16) -> K, [16,24) -> V (transposed out)
__global__ __launch_bounds__(256) void gemm_qkv(
    const u16* __restrict__ A,
    const u16* __restrict__ Wq, const u16* __restrict__ Wk, const u16* __restrict__ Wv,
    const float* __restrict__ bq, const float* __restrict__ bk, const float* __restrict__ bv,
    u16* __restrict__ Q, u16* __restrict__ K, u16* __restrict__ V)
{
    int nb = blockIdx.x;
    int which = nb >> 3;
    int n0 = (nb & 7) * 128;
    int m0 = blockIdx.y * 128;
    if (which == 0)      gemm128_body<true, false>(A, Wq, bq, Q, m0, n0, Cv, Cv);
    else if (which == 1) gemm128_body<true, false>(A, Wk, bk, K, m0, n0, Cv, Cv);
    else                 gemm128_body<true, true >(A, Wv, bv, V, m0, n0, Cv, Cv);
}

// output proj: 128x64 tiles, grid (16, 32) = 512 blocks (2/CU)
__global__ __launch_bounds__(256) void gemm_o64(
    const u16* __restrict__ A, const u16* __restrict__ Wt,
    const float* __restrict__ bias, float* __restrict__ outp)
{
    __shared__ u16 lA[128 * 32];
    __shared__ u16 lB[64 * 32];
    const int tid  = threadIdx.x;
    const int lane = tid & 63, w = tid >> 6;
    const int quad = lane >> 4, lm = lane & 15;
    const int m0 = blockIdx.y * 128, n0 = blockIdx.x * 64;
    const int K = Cv;

    f32x4 zero = {0.f, 0.f, 0.f, 0.f};
    f32x4 acc[2][4];
    #pragma unroll
    for (int mt = 0; mt < 2; mt++)
        #pragma unroll
        for (int nt = 0; nt < 4; nt++) acc[mt][nt] = zero;

    const int srow = lane >> 2, sseg = lane & 3;
    const u16* ga0 = A + (size_t)(m0 + w * 32 + srow) * K + sseg * 8;
    const u16* ga1 = ga0 + (size_t)16 * K;
    const u16* gb  = Wt + (size_t)(n0 + w * 16 + srow) * K + sseg * 8;
    u16* la0 = &lA[(w * 32) * 32];
    u16* la1 = &lA[(w * 32 + 16) * 32];
    u16* lb  = &lB[(w * 16) * 32];

    for (int k0 = 0; k0 < K; k0 += 32) {
        gl_lds16(ga0 + k0, la0);
        gl_lds16(ga1 + k0, la1);
        gl_lds16(gb + k0, lb);
        __syncthreads();
        bf16x8 af[2], bf[4];
        #pragma unroll
        for (int mt = 0; mt < 2; mt++)
            af[mt] = *(const bf16x8*)&lA[(w * 32 + mt * 16 + lm) * 32 + quad * 8];
        #pragma unroll
        for (int nt = 0; nt < 4; nt++)
            bf[nt] = *(const bf16x8*)&lB[(nt * 16 + lm) * 32 + quad * 8];
        #pragma unroll
        for (int mt = 0; mt < 2; mt++)
            #pragma unroll
            for (int nt = 0; nt < 4; nt++)
                acc[mt][nt] = MFMA16(af[mt], bf[nt], acc[mt][nt]);
        __syncthreads();
    }

    #pragma unroll
    for (int nt = 0; nt < 4; nt++) {
        int col = n0 + nt * 16 + lm;
        float bv = bias[col];
        #pragma unroll
        for (int mt = 0; mt < 2; mt++) {
            #pragma unroll
            for (int r = 0; r < 4; r++) {
                int row = m0 + w * 32 + mt * 16 + quad * 4 + r;
                outp[(size_t)row * Cv + col] = acc[mt][nt][r] + bv;
            }
        }
    }
}

// ---------------- flash attention: 128 q-rows/block, V^T input, all-gl_lds16 staging ----------------
// grid: (16, H, B), qt reversed; 4 waves, each 32 q-rows (2 m-tiles).
__global__ __launch_bounds__(256) void attn(
    const u16* __restrict__ Qp, const u16* __restrict__ Kp,
    const u16* __restrict__ VTg, u16* __restrict__ Op)
{
    __shared__ u16 lK[64 * 64];       // K-tile [key][d], cols XOR-swizzled by (key&7)
    __shared__ u16 lVT[64 * 64];      // V^T tile [d][key], cols XOR-swizzled by (d&7)
    __shared__ u16 lP[4][32][72];     // per-wave P [qrow][key], pad 72 (144B rows, 16B-aligned)

    const int tid  = threadIdx.x;
    const int lane = tid & 63, w = tid >> 6;
    const int quad = lane >> 4, lm = lane & 15;
    const int qt = 15 - blockIdx.x;   // reversed: long blocks first
    const int h = blockIdx.y, b = blockIdx.z;
    const int qb = qt * 128;
    const size_t headoff = (size_t)b * Tv * Cv + (size_t)h * Dv;
    const size_t vthead = (size_t)h * 64 * Mv + (size_t)b * Tv;

    // Q A-frags in regs: qf[ks][mt]
    bf16x8 qf[2][2];
    #pragma unroll
    for (int mt = 0; mt < 2; mt++) {
        const u16* qptr = Qp + headoff + (size_t)(qb + w * 32 + mt * 16 + lm) * Cv + quad * 8;
        qf[0][mt] = *(const bf16x8*)(qptr);
        qf[1][mt] = *(const bf16x8*)(qptr + 32);
    }

    f32x4 zero = {0.f, 0.f, 0.f, 0.f};
    f32x4 oacc[2][4];
    #pragma unroll
    for (int mt = 0; mt < 2; mt++)
        #pragma unroll
        for (int nt = 0; nt < 4; nt++) oacc[mt][nt] = zero;
    float Lp[2][4] = {{0.f,0.f,0.f,0.f},{0.f,0.f,0.f,0.f}};

    const float SC = 0.18033688011112042f;  // (1/sqrt(64)) * log2(e)
    const int rowi = lane >> 3, seg = lane & 7;
    const int niter = qt * 2 + 2;

    for (int kt = 0; kt < niter; kt++) {
        const int k0 = kt * 64;
        // ---- stage K and V^T via swizzled gl_lds16 (4 instr/wave) ----
        #pragma unroll
        for (int half = 0; half < 2; half++) {
            int rbase = w * 16 + half * 8;
            int row = rbase + rowi;
            int gseg = seg ^ (row & 7);
            gl_lds16(Kp + headoff + (size_t)(k0 + row) * Cv + gseg * 8, &lK[rbase * 64]);
            gl_lds16(VTg + vthead + (size_t)row * Mv + k0 + gseg * 8, &lVT[rbase * 64]);
        }
        __syncthreads();

        // ---- S = Q K^T (kf reused across both m-tiles) ----
        f32x4 sacc[2][4];
        #pragma unroll
        for (int mt = 0; mt < 2; mt++)
            #pragma unroll
            for (int nt = 0; nt < 4; nt++) sacc[mt][nt] = zero;
        #pragma unroll
        for (int ks = 0; ks < 2; ks++) {
            #pragma unroll
            for (int nt = 0; nt < 4; nt++) {
                bf16x8 kf = *(const bf16x8*)
                    &lK[(nt * 16 + lm) * 64 + (((ks * 4 + quad) ^ (lm & 7)) * 8)];
                #pragma unroll
                for (int mt = 0; mt < 2; mt++)
                    sacc[mt][nt] = MFMA16(qf[ks][mt], kf, sacc[mt][nt]);
            }
        }

        // ---- fixed-exponent softmax: p = exp2(s*SC - 16), scale cancels in O/L ----
        const bool needmask = (kt >= niter - 2);
        #pragma unroll
        for (int mt = 0; mt < 2; mt++) {
            #pragma unroll
            for (int r = 0; r < 4; r++) {
                const int qrow = qb + w * 32 + mt * 16 + quad * 4 + r;
                #pragma unroll
                for (int nt = 0; nt < 4; nt++) {
                    float e = __builtin_amdgcn_exp2f(fmaf(sacc[mt][nt][r], SC, -16.f));
                    if (needmask && (k0 + nt * 16 + lm > qrow)) e = 0.f;
                    Lp[mt][r] += e;
                    lP[w][mt * 16 + quad * 4 + r][nt * 16 + lm] = (u16)(__float_as_uint(e) >> 16);
                }
            }
        }

        // ---- O += P V (vf reused across both m-tiles) ----
        #pragma unroll
        for (int ks = 0; ks < 2; ks++) {
            bf16x8 pf[2];
            #pragma unroll
            for (int mt = 0; mt < 2; mt++)
                pf[mt] = *(const bf16x8*)&lP[w][mt * 16 + lm][ks * 32 + quad * 8];
            #pragma unroll
            for (int nt = 0; nt < 4; nt++) {
                bf16x8 vf = *(const bf16x8*)
                    &lVT[(nt * 16 + lm) * 64 + (((ks * 4 + quad) ^ (lm & 7)) * 8)];
                #pragma unroll
                for (int mt = 0; mt < 2; mt++)
                    oacc[mt][nt] = MFMA16(pf[mt], vf, oacc[mt][nt]);
            }
        }
        __syncthreads();
    }

    // ---- epilogue: deferred L reduction (over lm 16-group), then O/L ----
    #pragma unroll
    for (int mt = 0; mt < 2; mt++) {
        float inv[4];
        #pragma unroll
        for (int r = 0; r < 4; r++) {
            float L = Lp[mt][r];
            #pragma unroll
            for (int off = 1; off < 16; off <<= 1)
                L += __shfl_xor(L, off, 64);
            inv[r] = 1.0f / L;
        }
        #pragma unroll
        for (int nt = 0; nt < 4; nt++) {
            #pragma unroll
            for (int r = 0; r < 4; r++) {
                int row = qb + w * 32 + mt * 16 + quad * 4 + r;
                Op[headoff + (size_t)row * Cv + nt * 16 + lm] = f2bf(oacc[mt][nt][r] * inv[r]);
            }
        }
    }
}

// ---------------- launcher ----------------
extern "C" void kernel_launch(void* const* d_in, const int* in_sizes, int n_in,
                              void* d_out, int out_size, void* d_ws, size_t ws_size,
                              hipStream_t stream) {
    const float* x  = (const float*)d_in[0];
    const float* Wq = (const float*)d_in[1];
    const float* bq = (const float*)d_in[2];
    const float* Wk = (const float*)d_in[3];
    const float* bk = (const float*)d_in[4];
    const float* Wv = (const float*)d_in[5];
    const float* bv = (const float*)d_in[6];
    const float* Wo = (const float*)d_in[7];
    const float* bo = (const float*)d_in[8];
    u16* ws = (u16*)d_ws;

    convert_all<<<8192, 256, 0, stream>>>(x, Wq, Wk, Wv, Wo, ws);

    gemm_qkv<<<dim3(24, 32), 256, 0, stream>>>(
        ws + OFF_XB, ws + OFF_WQ, ws + OFF_WK, ws + OFF_WV,
        bq, bk, bv, ws + OFF_Q, ws + OFF_K, ws + OFF_V);

    attn<<<dim3(16, Hv, Bv), 256, 0, stream>>>(ws + OFF_Q, ws + OFF_K, ws + OFF_V, ws + OFF_A);

    gemm_o64<<<dim3(16, 32), 256, 0, stream>>>(ws + OFF_A, ws + OFF_WO, bo, (float*)d_out);
}

// Round 4
// 197.856 us; speedup vs baseline: 1.1540x; 1.1540x over previous
//
#include <hip/hip_runtime.h>

typedef unsigned short u16;
typedef __attribute__((ext_vector_type(8))) __bf16 bf16x8;
typedef __attribute__((ext_vector_type(4))) float f32x4;
typedef __attribute__((ext_vector_type(4))) unsigned int u32x4;

#define MFMA16(a, b, c) __builtin_amdgcn_mfma_f32_16x16x32_bf16(a, b, c, 0, 0, 0)

__device__ __forceinline__ u16 f2bf(float f) {
    unsigned u = __float_as_uint(f);
    u = (u + 0x7FFFu + ((u >> 16) & 1u)) >> 16;
    return (u16)u;
}

// async global->LDS, 16B per lane; LDS dest = wave-uniform base + lane*16
__device__ __forceinline__ void gl_lds16(const u16* g, u16* l) {
    __builtin_amdgcn_global_load_lds(
        (const __attribute__((address_space(1))) unsigned int*)g,
        (__attribute__((address_space(3))) unsigned int*)l, 16, 0, 0);
}

static constexpr int Bv = 2, Tv = 2048, Cv = 1024, Hv = 16, Dv = 64;
static constexpr int Mv = Bv * Tv; // 4096

// ws element offsets (u16 elements)
static constexpr size_t OFF_XB = 0;                      // x bf16       [4096,1024]
static constexpr size_t OFF_WQ = 4194304;                // Wq bf16      [1024,1024]
static constexpr size_t OFF_WK = OFF_WQ + 1048576;
static constexpr size_t OFF_WV = OFF_WK + 1048576;
static constexpr size_t OFF_WO = OFF_WV + 1048576;
static constexpr size_t OFF_Q  = OFF_WO + 1048576;       // Q bf16 [M, C]
static constexpr size_t OFF_K  = OFF_Q + 4194304;        // K bf16 [M, C]
static constexpr size_t OFF_V  = OFF_K + 4194304;        // V bf16 [M, C]
static constexpr size_t OFF_A  = OFF_V + 4194304;        // attended bf16 [M, C]
static constexpr size_t OFF_VT = OFF_A + 4194304;        // V^T bf16 [C, M]

// ---------------- fp32 -> bf16 convert (x + 4 weights) ----------------
__global__ __launch_bounds__(256) void convert_all(
    const float* __restrict__ x,
    const float* __restrict__ wq, const float* __restrict__ wk,
    const float* __restrict__ wv, const float* __restrict__ wo,
    u16* __restrict__ dst)
{
    int i4 = blockIdx.x * blockDim.x + threadIdx.x;
    if (i4 >= 2097152) return;
    int idx = i4 * 4;
    const float* src; int off;
    if (idx < 4194304) { src = x; off = idx; }
    else {
        int rel = idx - 4194304;
        int j = rel >> 20;
        off = rel & 1048575;
        src = (j == 0) ? wq : (j == 1) ? wk : (j == 2) ? wv : wo;
    }
    float4 v = *(const float4*)(src + off);
    ushort4 o;
    o.x = f2bf(v.x); o.y = f2bf(v.y); o.z = f2bf(v.z); o.w = f2bf(v.w);
    *(ushort4*)(dst + idx) = o;
}

// ---------------- 128x128-tile bf16 GEMM body (m97 structure) ----------------
template <bool OUT_BF16>
__device__ __forceinline__ void gemm128_body(
    const u16* __restrict__ A, const u16* __restrict__ Wt,
    const float* __restrict__ bias, void* __restrict__ outp,
    int m0, int n0, int N, int K)
{
    __shared__ u16 lA[128 * 32];
    __shared__ u16 lB[128 * 32];
    const int tid  = threadIdx.x;
    const int lane = tid & 63, w = tid >> 6;
    const int quad = lane >> 4, lm = lane & 15;
    const int wm = (w & 1) * 64, wn = (w >> 1) * 64;

    f32x4 zero = {0.f, 0.f, 0.f, 0.f};
    f32x4 acc[4][4];
    #pragma unroll
    for (int mt = 0; mt < 4; mt++)
        #pragma unroll
        for (int nt = 0; nt < 4; nt++) acc[mt][nt] = zero;

    const int srow = lane >> 2, sseg = lane & 3;
    const u16* ga0 = A  + (size_t)(m0 + w * 16 + srow) * K + sseg * 8;
    const u16* ga1 = ga0 + (size_t)64 * K;
    const u16* gb0 = Wt + (size_t)(n0 + w * 16 + srow) * K + sseg * 8;
    const u16* gb1 = gb0 + (size_t)64 * K;
    u16* la0 = &lA[(w * 16) * 32];      u16* la1 = &lA[(64 + w * 16) * 32];
    u16* lb0 = &lB[(w * 16) * 32];      u16* lb1 = &lB[(64 + w * 16) * 32];

    for (int k0 = 0; k0 < K; k0 += 32) {
        gl_lds16(ga0 + k0, la0);
        gl_lds16(ga1 + k0, la1);
        gl_lds16(gb0 + k0, lb0);
        gl_lds16(gb1 + k0, lb1);
        __syncthreads();
        bf16x8 af[4], bf[4];
        #pragma unroll
        for (int mt = 0; mt < 4; mt++)
            af[mt] = *(const bf16x8*)&lA[(wm + mt * 16 + lm) * 32 + quad * 8];
        #pragma unroll
        for (int nt = 0; nt < 4; nt++)
            bf[nt] = *(const bf16x8*)&lB[(wn + nt * 16 + lm) * 32 + quad * 8];
        #pragma unroll
        for (int mt = 0; mt < 4; mt++)
            #pragma unroll
            for (int nt = 0; nt < 4; nt++)
                acc[mt][nt] = MFMA16(af[mt], bf[nt], acc[mt][nt]);
        __syncthreads();
    }

    #pragma unroll
    for (int nt = 0; nt < 4; nt++) {
        int col = n0 + wn + nt * 16 + lm;
        float bv = bias[col];
        #pragma unroll
        for (int mt = 0; mt < 4; mt++) {
            #pragma unroll
            for (int r = 0; r < 4; r++) {
                int row = m0 + wm + mt * 16 + quad * 4 + r;
                float v = acc[mt][nt][r] + bv;
                if (OUT_BF16) ((u16*)outp)[(size_t)row * N + col] = f2bf(v);
                else          ((float*)outp)[(size_t)row * N + col] = v;
            }
        }
    }
}

// fused QKV: grid (24, 32); all outputs row-major [M, C]
__global__ __launch_bounds__(256) void gemm_qkv(
    const u16* __restrict__ A,
    const u16* __restrict__ Wq, const u16* __restrict__ Wk, const u16* __restrict__ Wv,
    const float* __restrict__ bq, const float* __restrict__ bk, const float* __restrict__ bv,
    u16* __restrict__ Q, u16* __restrict__ K, u16* __restrict__ V)
{
    int nb = blockIdx.x;
    int which = nb >> 3;
    int n0 = (nb & 7) * 128;
    int m0 = blockIdx.y * 128;
    const u16* Wt = (which == 0) ? Wq : (which == 1) ? Wk : Wv;
    const float* bias = (which == 0) ? bq : (which == 1) ? bk : bv;
    u16* out = (which == 0) ? Q : (which == 1) ? K : V;
    gemm128_body<true>(A, Wt, bias, out, m0, n0, Cv, Cv);
}

// ---------------- V [Mv,Cv] -> VT [Cv,Mv], LDS-tiled transpose ----------------
__global__ __launch_bounds__(256) void transpose_v(
    const u16* __restrict__ V, u16* __restrict__ VT)
{
    __shared__ u16 t[64][72];
    const int m0 = blockIdx.x * 64, c0 = blockIdx.y * 64;
    const int tid = threadIdx.x;
    const int mr = tid >> 3, cs = tid & 7;
    *(u32x4*)&t[mr][cs * 8]      = *(const u32x4*)(V + (size_t)(m0 + mr) * Cv + c0 + cs * 8);
    *(u32x4*)&t[mr + 32][cs * 8] = *(const u32x4*)(V + (size_t)(m0 + mr + 32) * Cv + c0 + cs * 8);
    __syncthreads();
    const int cr = tid >> 3, ms = tid & 7;
    #pragma unroll
    for (int h2 = 0; h2 < 2; h2++) {
        int c = cr + h2 * 32;
        ushort4 o0, o1;
        o0.x = t[ms * 8 + 0][c]; o0.y = t[ms * 8 + 1][c];
        o0.z = t[ms * 8 + 2][c]; o0.w = t[ms * 8 + 3][c];
        o1.x = t[ms * 8 + 4][c]; o1.y = t[ms * 8 + 5][c];
        o1.z = t[ms * 8 + 6][c]; o1.w = t[ms * 8 + 7][c];
        u16* dst = VT + (size_t)(c0 + c) * Mv + m0 + ms * 8;
        *(ushort4*)(dst)     = o0;
        *(ushort4*)(dst + 4) = o1;
    }
}

// output proj: 128x64 tiles, grid (16, 32)
__global__ __launch_bounds__(256) void gemm_o64(
    const u16* __restrict__ A, const u16* __restrict__ Wt,
    const float* __restrict__ bias, float* __restrict__ outp)
{
    __shared__ u16 lA[128 * 32];
    __shared__ u16 lB[64 * 32];
    const int tid  = threadIdx.x;
    const int lane = tid & 63, w = tid >> 6;
    const int quad = lane >> 4, lm = lane & 15;
    const int m0 = blockIdx.y * 128, n0 = blockIdx.x * 64;
    const int K = Cv;

    f32x4 zero = {0.f, 0.f, 0.f, 0.f};
    f32x4 acc[2][4];
    #pragma unroll
    for (int mt = 0; mt < 2; mt++)
        #pragma unroll
        for (int nt = 0; nt < 4; nt++) acc[mt][nt] = zero;

    const int srow = lane >> 2, sseg = lane & 3;
    const u16* ga0 = A + (size_t)(m0 + w * 32 + srow) * K + sseg * 8;
    const u16* ga1 = ga0 + (size_t)16 * K;
    const u16* gb  = Wt + (size_t)(n0 + w * 16 + srow) * K + sseg * 8;
    u16* la0 = &lA[(w * 32) * 32];
    u16* la1 = &lA[(w * 32 + 16) * 32];
    u16* lb  = &lB[(w * 16) * 32];

    for (int k0 = 0; k0 < K; k0 += 32) {
        gl_lds16(ga0 + k0, la0);
        gl_lds16(ga1 + k0, la1);
        gl_lds16(gb + k0, lb);
        __syncthreads();
        bf16x8 af[2], bf[4];
        #pragma unroll
        for (int mt = 0; mt < 2; mt++)
            af[mt] = *(const bf16x8*)&lA[(w * 32 + mt * 16 + lm) * 32 + quad * 8];
        #pragma unroll
        for (int nt = 0; nt < 4; nt++)
            bf[nt] = *(const bf16x8*)&lB[(nt * 16 + lm) * 32 + quad * 8];
        #pragma unroll
        for (int mt = 0; mt < 2; mt++)
            #pragma unroll
            for (int nt = 0; nt < 4; nt++)
                acc[mt][nt] = MFMA16(af[mt], bf[nt], acc[mt][nt]);
        __syncthreads();
    }

    #pragma unroll
    for (int nt = 0; nt < 4; nt++) {
        int col = n0 + nt * 16 + lm;
        float bv = bias[col];
        #pragma unroll
        for (int mt = 0; mt < 2; mt++) {
            #pragma unroll
            for (int r = 0; r < 4; r++) {
                int row = m0 + w * 32 + mt * 16 + quad * 4 + r;
                outp[(size_t)row * Cv + col] = acc[mt][nt][r] + bv;
            }
        }
    }
}

// ---------------- flash attention v4 ----------------
// 1-D grid of 512: block c and c+256 share (b,h), complementary qt -> 36 iters/CU.
// Double-buffered K/VT staging (one barrier/iter). S^T operand swap -> b64 P stores.
__global__ __launch_bounds__(256) void attn(
    const u16* __restrict__ Qp, const u16* __restrict__ Kp,
    const u16* __restrict__ VTg, u16* __restrict__ Op)
{
    __shared__ u16 lK[2][64 * 64];    // K-tile [key][d], cols XOR-swizzled by (key&7)
    __shared__ u16 lVT[2][64 * 64];   // V^T tile [d][key], cols XOR-swizzled by (d&7)
    __shared__ u16 lP[4][32][72];     // per-wave P [qrow][key], stride 72

    const int tid  = threadIdx.x;
    const int lane = tid & 63, w = tid >> 6;
    const int quad = lane >> 4, lm = lane & 15;

    const int idx  = blockIdx.x;
    const int half = idx >> 8;
    const int grp  = idx & 255;
    const int bh   = grp >> 3;
    const int j    = grp & 7;
    const int qt   = half ? j : 15 - j;   // c & c+256: complementary qt, same bh
    const int h = bh & 15, b = bh >> 4;

    const int qb = qt * 128;
    const size_t headoff = (size_t)b * Tv * Cv + (size_t)h * Dv;
    const size_t vthead  = (size_t)h * 64 * Mv + (size_t)b * Tv;

    // Q frags (used as B-operand; same per-lane layout as A): qf[ks][nt]
    bf16x8 qf[2][2];
    #pragma unroll
    for (int nt = 0; nt < 2; nt++) {
        const u16* qptr = Qp + headoff + (size_t)(qb + w * 32 + nt * 16 + lm) * Cv + quad * 8;
        qf[0][nt] = *(const bf16x8*)(qptr);
        qf[1][nt] = *(const bf16x8*)(qptr + 32);
    }

    f32x4 zero = {0.f, 0.f, 0.f, 0.f};
    f32x4 oacc[2][4];
    #pragma unroll
    for (int mt = 0; mt < 2; mt++)
        #pragma unroll
        for (int nt = 0; nt < 4; nt++) oacc[mt][nt] = zero;
    float Lp[2] = {0.f, 0.f};

    const float SC = 0.18033688011112042f;  // (1/sqrt(64)) * log2(e)
    const int rowi = lane >> 3, seg = lane & 7;
    const int niter = qt * 2 + 2;

    // stage tile kt into buffer bsel
    auto stage = [&](int bsel, int kt) {
        const int k0 = kt * 64;
        #pragma unroll
        for (int hf = 0; hf < 2; hf++) {
            int rbase = w * 16 + hf * 8;
            int row = rbase + rowi;
            int gseg = seg ^ (row & 7);
            gl_lds16(Kp + headoff + (size_t)(k0 + row) * Cv + gseg * 8, &lK[bsel][rbase * 64]);
            gl_lds16(VTg + vthead + (size_t)row * Mv + k0 + gseg * 8, &lVT[bsel][rbase * 64]);
        }
    };

    stage(0, 0);

    for (int kt = 0; kt < niter; kt++) {
        const int bsel = kt & 1;
        const int k0 = kt * 64;
        __syncthreads();                       // buf bsel ready; prior reads drained
        if (kt + 1 < niter) stage(bsel ^ 1, kt + 1);

        // ---- S^T = K Q^T: tiles stt[mt=key(4)][nt=qrow(2)] ----
        f32x4 stt[4][2];
        #pragma unroll
        for (int mt = 0; mt < 4; mt++)
            #pragma unroll
            for (int nt = 0; nt < 2; nt++) stt[mt][nt] = zero;
        #pragma unroll
        for (int ks = 0; ks < 2; ks++) {
            #pragma unroll
            for (int mt = 0; mt < 4; mt++) {
                bf16x8 kf = *(const bf16x8*)
                    &lK[bsel][(mt * 16 + lm) * 64 + (((ks * 4 + quad) ^ (lm & 7)) * 8)];
                #pragma unroll
                for (int nt = 0; nt < 2; nt++)
                    stt[mt][nt] = MFMA16(kf, qf[ks][nt], stt[mt][nt]);
            }
        }

        // ---- softmax: p = exp2(s*SC - 16); lane holds 4 consecutive keys -> b64 store ----
        const bool needmask = (kt >= niter - 2);
        #pragma unroll
        for (int mt = 0; mt < 4; mt++) {
            #pragma unroll
            for (int nt = 0; nt < 2; nt++) {
                const int keyb = k0 + mt * 16 + quad * 4;
                const int qrow = qb + w * 32 + nt * 16 + lm;
                ushort4 pk;
                float e0 = __builtin_amdgcn_exp2f(fmaf(stt[mt][nt][0], SC, -16.f));
                float e1 = __builtin_amdgcn_exp2f(fmaf(stt[mt][nt][1], SC, -16.f));
                float e2 = __builtin_amdgcn_exp2f(fmaf(stt[mt][nt][2], SC, -16.f));
                float e3 = __builtin_amdgcn_exp2f(fmaf(stt[mt][nt][3], SC, -16.f));
                if (needmask) {
                    if (keyb + 0 > qrow) e0 = 0.f;
                    if (keyb + 1 > qrow) e1 = 0.f;
                    if (keyb + 2 > qrow) e2 = 0.f;
                    if (keyb + 3 > qrow) e3 = 0.f;
                }
                Lp[nt] += e0 + e1 + e2 + e3;
                pk.x = (u16)(__float_as_uint(e0) >> 16);
                pk.y = (u16)(__float_as_uint(e1) >> 16);
                pk.z = (u16)(__float_as_uint(e2) >> 16);
                pk.w = (u16)(__float_as_uint(e3) >> 16);
                *(ushort4*)&lP[w][nt * 16 + lm][mt * 16 + quad * 4] = pk;
            }
        }

        // ---- O += P V (A=P from lP rows; B=V from lVT) ----
        #pragma unroll
        for (int ks = 0; ks < 2; ks++) {
            bf16x8 pf[2];
            #pragma unroll
            for (int mt = 0; mt < 2; mt++)
                pf[mt] = *(const bf16x8*)&lP[w][mt * 16 + lm][ks * 32 + quad * 8];
            #pragma unroll
            for (int nt = 0; nt < 4; nt++) {
                bf16x8 vf = *(const bf16x8*)
                    &lVT[bsel][(nt * 16 + lm) * 64 + (((ks * 4 + quad) ^ (lm & 7)) * 8)];
                #pragma unroll
                for (int mt = 0; mt < 2; mt++)
                    oacc[mt][nt] = MFMA16(pf[mt], vf, oacc[mt][nt]);
            }
        }
    }

    // ---- epilogue: L reduce over quads, redistribute to O-row mapping, write ----
    float Lred[2];
    #pragma unroll
    for (int nt = 0; nt < 2; nt++) {
        float L = Lp[nt];
        L += __shfl_xor(L, 16, 64);
        L += __shfl_xor(L, 32, 64);
        Lred[nt] = 1.0f / L;   // inv of L for qrow = nt*16 + lm (valid in all quads)
    }
    #pragma unroll
    for (int mt = 0; mt < 2; mt++) {
        float inv[4];
        #pragma unroll
        for (int r = 0; r < 4; r++)
            inv[r] = __shfl(Lred[mt], (lane & 48) | (quad * 4 + r), 64);
        #pragma unroll
        for (int nt = 0; nt < 4; nt++) {
            #pragma unroll
            for (int r = 0; r < 4; r++) {
                int row = qb + w * 32 + mt * 16 + quad * 4 + r;
                Op[headoff + (size_t)row * Cv + nt * 16 + lm] = f2bf(oacc[mt][nt][r] * inv[r]);
            }
        }
    }
}

// ---------------- launcher ----------------
extern "C" void kernel_launch(void* const* d_in, const int* in_sizes, int n_in,
                              void* d_out, int out_size, void* d_ws, size_t ws_size,
                              hipStream_t stream) {
    const float* x  = (const float*)d_in[0];
    const float* Wq = (const float*)d_in[1];
    const float* bq = (const float*)d_in[2];
    const float* Wk = (const float*)d_in[3];
    const float* bk = (const float*)d_in[4];
    const float* Wv = (const float*)d_in[5];
    const float* bv = (const float*)d_in[6];
    const float* Wo = (const float*)d_in[7];
    const float* bo = (const float*)d_in[8];
    u16* ws = (u16*)d_ws;

    convert_all<<<8192, 256, 0, stream>>>(x, Wq, Wk, Wv, Wo, ws);

    gemm_qkv<<<dim3(24, 32), 256, 0, stream>>>(
        ws + OFF_XB, ws + OFF_WQ, ws + OFF_WK, ws + OFF_WV,
        bq, bk, bv, ws + OFF_Q, ws + OFF_K, ws + OFF_V);

    transpose_v<<<dim3(Mv / 64, Cv / 64), 256, 0, stream>>>(ws + OFF_V, ws + OFF_VT);

    attn<<<512, 256, 0, stream>>>(ws + OFF_Q, ws + OFF_K, ws + OFF_VT, ws + OFF_A);

    gemm_o64<<<dim3(16, 32), 256, 0, stream>>>(ws + OFF_A, ws + OFF_WO, bo, (float*)d_out);
}

// Round 5
// 196.412 us; speedup vs baseline: 1.1625x; 1.0074x over previous
//
#include <hip/hip_runtime.h>

typedef unsigned short u16;
typedef __attribute__((ext_vector_type(8))) __bf16 bf16x8;
typedef __attribute__((ext_vector_type(4))) float f32x4;
typedef __attribute__((ext_vector_type(4))) unsigned int u32x4;

#define MFMA16(a, b, c) __builtin_amdgcn_mfma_f32_16x16x32_bf16(a, b, c, 0, 0, 0)

__device__ __forceinline__ u16 f2bf(float f) {
    unsigned u = __float_as_uint(f);
    u = (u + 0x7FFFu + ((u >> 16) & 1u)) >> 16;
    return (u16)u;
}

// async global->LDS, 16B per lane; LDS dest = wave-uniform base + lane*16
__device__ __forceinline__ void gl_lds16(const u16* g, u16* l) {
    __builtin_amdgcn_global_load_lds(
        (const __attribute__((address_space(1))) unsigned int*)g,
        (__attribute__((address_space(3))) unsigned int*)l, 16, 0, 0);
}

static constexpr int Bv = 2, Tv = 2048, Cv = 1024, Hv = 16, Dv = 64;
static constexpr int Mv = Bv * Tv; // 4096

// ws element offsets (u16 elements)
static constexpr size_t OFF_XB = 0;                      // x bf16       [4096,1024]
static constexpr size_t OFF_WQ = 4194304;                // Wq bf16      [1024,1024]
static constexpr size_t OFF_WK = OFF_WQ + 1048576;
static constexpr size_t OFF_WV = OFF_WK + 1048576;
static constexpr size_t OFF_WO = OFF_WV + 1048576;
static constexpr size_t OFF_Q  = OFF_WO + 1048576;       // Q bf16 [M, C]
static constexpr size_t OFF_K  = OFF_Q + 4194304;        // K bf16 [M, C]
static constexpr size_t OFF_VT = OFF_K + 4194304;        // V^T bf16 [C, M]
static constexpr size_t OFF_A  = OFF_VT + 4194304;       // attended bf16 [M, C]

// ---------------- fp32 -> bf16 convert (x + 4 weights) ----------------
__global__ __launch_bounds__(256) void convert_all(
    const float* __restrict__ x,
    const float* __restrict__ wq, const float* __restrict__ wk,
    const float* __restrict__ wv, const float* __restrict__ wo,
    u16* __restrict__ dst)
{
    int i4 = blockIdx.x * blockDim.x + threadIdx.x;
    if (i4 >= 2097152) return;
    int idx = i4 * 4;
    const float* src; int off;
    if (idx < 4194304) { src = x; off = idx; }
    else {
        int rel = idx - 4194304;
        int j = rel >> 20;
        off = rel & 1048575;
        src = (j == 0) ? wq : (j == 1) ? wk : (j == 2) ? wv : wo;
    }
    float4 v = *(const float4*)(src + off);
    ushort4 o;
    o.x = f2bf(v.x); o.y = f2bf(v.y); o.z = f2bf(v.z); o.w = f2bf(v.w);
    *(ushort4*)(dst + idx) = o;
}

// ---------------- 128x128-tile bf16 GEMM, BK=64, XOR-swizzled LDS ----------------
// out[M,N] = A[M,K] * W[N,K]^T + bias. 4 waves 2x2, each 64x64.
// ROWBIAS: bias indexed by output row (for the operand-swapped V^T GEMM).
template <bool OUT_BF16, bool ROWBIAS>
__device__ __forceinline__ void gemm128_b64(
    const u16* __restrict__ A, const u16* __restrict__ Wt,
    const float* __restrict__ bias, void* __restrict__ outp,
    int m0, int n0, int N, int K)
{
    __shared__ u16 lA[128 * 64];   // [row][64], cols XOR-swizzled by (row&7)
    __shared__ u16 lB[128 * 64];
    const int tid  = threadIdx.x;
    const int lane = tid & 63, w = tid >> 6;
    const int quad = lane >> 4, lm = lane & 15;
    const int wm = (w & 1) * 64, wn = (w >> 1) * 64;

    f32x4 zero = {0.f, 0.f, 0.f, 0.f};
    f32x4 acc[4][4];
    #pragma unroll
    for (int mt = 0; mt < 4; mt++)
        #pragma unroll
        for (int nt = 0; nt < 4; nt++) acc[mt][nt] = zero;

    const int rowi = lane >> 3, seg = lane & 7;   // 8 rows x 8 segs(16B) per instr

    for (int k0 = 0; k0 < K; k0 += 64) {
        // wave w stages rows [w*32, w*32+32) of A and B: 4+4 gl_lds16
        #pragma unroll
        for (int i = 0; i < 4; i++) {
            int rbase = w * 32 + i * 8;
            int row = rbase + rowi;
            int gseg = seg ^ (row & 7);
            gl_lds16(A  + (size_t)(m0 + row) * K + k0 + gseg * 8, &lA[rbase * 64]);
            gl_lds16(Wt + (size_t)(n0 + row) * K + k0 + gseg * 8, &lB[rbase * 64]);
        }
        __syncthreads();
        #pragma unroll
        for (int ks = 0; ks < 2; ks++) {
            const int swz = ((ks * 4 + quad) ^ (lm & 7)) * 8;
            bf16x8 af[4], bf[4];
            #pragma unroll
            for (int mt = 0; mt < 4; mt++)
                af[mt] = *(const bf16x8*)&lA[(wm + mt * 16 + lm) * 64 + swz];
            #pragma unroll
            for (int nt = 0; nt < 4; nt++)
                bf[nt] = *(const bf16x8*)&lB[(wn + nt * 16 + lm) * 64 + swz];
            #pragma unroll
            for (int mt = 0; mt < 4; mt++)
                #pragma unroll
                for (int nt = 0; nt < 4; nt++)
                    acc[mt][nt] = MFMA16(af[mt], bf[nt], acc[mt][nt]);
        }
        __syncthreads();
    }

    #pragma unroll
    for (int nt = 0; nt < 4; nt++) {
        int col = n0 + wn + nt * 16 + lm;
        float cb = ROWBIAS ? 0.f : bias[col];
        #pragma unroll
        for (int mt = 0; mt < 4; mt++) {
            #pragma unroll
            for (int r = 0; r < 4; r++) {
                int row = m0 + wm + mt * 16 + quad * 4 + r;
                float v = acc[mt][nt][r] + (ROWBIAS ? bias[row] : cb);
                if (OUT_BF16) ((u16*)outp)[(size_t)row * N + col] = f2bf(v);
                else          ((float*)outp)[(size_t)row * N + col] = v;
            }
        }
    }
}

// fused QKV: grid (24, 32).
// x in [0,8): Q = x@Wq^T [4096,1024]; [8,16): K likewise; [16,24): V^T = Wv@x^T [1024,4096].
__global__ __launch_bounds__(256) void gemm_qkv(
    const u16* __restrict__ A,
    const u16* __restrict__ Wq, const u16* __restrict__ Wk, const u16* __restrict__ Wv,
    const float* __restrict__ bq, const float* __restrict__ bk, const float* __restrict__ bv,
    u16* __restrict__ Q, u16* __restrict__ K, u16* __restrict__ VT)
{
    int nb = blockIdx.x;
    int which = nb >> 3;
    if (which == 0) {
        gemm128_b64<true, false>(A, Wq, bq, Q, blockIdx.y * 128, (nb & 7) * 128, Cv, Cv);
    } else if (which == 1) {
        gemm128_b64<true, false>(A, Wk, bk, K, blockIdx.y * 128, (nb & 7) * 128, Cv, Cv);
    } else {
        // V^T: rows = channel c (M'=1024), cols = token m (N'=4096); A'=Wv, B'=x; bias by row
        gemm128_b64<true, true>(Wv, A, bv, VT, (nb & 7) * 128, blockIdx.y * 128, Mv, Cv);
    }
}

// output proj: 128x64 tiles, BK=64, grid (16, 32)
__global__ __launch_bounds__(256) void gemm_o64(
    const u16* __restrict__ A, const u16* __restrict__ Wt,
    const float* __restrict__ bias, float* __restrict__ outp)
{
    __shared__ u16 lA[128 * 64];
    __shared__ u16 lB[64 * 64];
    const int tid  = threadIdx.x;
    const int lane = tid & 63, w = tid >> 6;
    const int quad = lane >> 4, lm = lane & 15;
    const int m0 = blockIdx.y * 128, n0 = blockIdx.x * 64;
    const int K = Cv;

    f32x4 zero = {0.f, 0.f, 0.f, 0.f};
    f32x4 acc[2][4];
    #pragma unroll
    for (int mt = 0; mt < 2; mt++)
        #pragma unroll
        for (int nt = 0; nt < 4; nt++) acc[mt][nt] = zero;

    const int rowi = lane >> 3, seg = lane & 7;

    for (int k0 = 0; k0 < K; k0 += 64) {
        #pragma unroll
        for (int i = 0; i < 4; i++) {
            int rbase = w * 32 + i * 8;
            int row = rbase + rowi;
            int gseg = seg ^ (row & 7);
            gl_lds16(A + (size_t)(m0 + row) * K + k0 + gseg * 8, &lA[rbase * 64]);
        }
        {
            int rbase = w * 16, row0 = rbase + rowi, row1 = row0 + 8;
            gl_lds16(Wt + (size_t)(n0 + row0) * K + k0 + (seg ^ (row0 & 7)) * 8, &lB[rbase * 64]);
            gl_lds16(Wt + (size_t)(n0 + row1) * K + k0 + (seg ^ (row1 & 7)) * 8, &lB[(rbase + 8) * 64]);
        }
        __syncthreads();
        #pragma unroll
        for (int ks = 0; ks < 2; ks++) {
            const int swz = ((ks * 4 + quad) ^ (lm & 7)) * 8;
            bf16x8 af[2], bf[4];
            #pragma unroll
            for (int mt = 0; mt < 2; mt++)
                af[mt] = *(const bf16x8*)&lA[(w * 32 + mt * 16 + lm) * 64 + swz];
            #pragma unroll
            for (int nt = 0; nt < 4; nt++)
                bf[nt] = *(const bf16x8*)&lB[(nt * 16 + lm) * 64 + swz];
            #pragma unroll
            for (int mt = 0; mt < 2; mt++)
                #pragma unroll
                for (int nt = 0; nt < 4; nt++)
                    acc[mt][nt] = MFMA16(af[mt], bf[nt], acc[mt][nt]);
        }
        __syncthreads();
    }

    #pragma unroll
    for (int nt = 0; nt < 4; nt++) {
        int col = n0 + nt * 16 + lm;
        float bvv = bias[col];
        #pragma unroll
        for (int mt = 0; mt < 2; mt++) {
            #pragma unroll
            for (int r = 0; r < 4; r++) {
                int row = m0 + w * 32 + mt * 16 + quad * 4 + r;
                outp[(size_t)row * Cv + col] = acc[mt][nt][r] + bvv;
            }
        }
    }
}

// ---------------- flash attention (unchanged from R4) ----------------
// 1-D grid of 512: block c and c+256 share (b,h), complementary qt -> 36 iters/CU.
// Double-buffered K/VT staging (one barrier/iter). S^T operand swap -> b64 P stores.
__global__ __launch_bounds__(256) void attn(
    const u16* __restrict__ Qp, const u16* __restrict__ Kp,
    const u16* __restrict__ VTg, u16* __restrict__ Op)
{
    __shared__ u16 lK[2][64 * 64];    // K-tile [key][d], cols XOR-swizzled by (key&7)
    __shared__ u16 lVT[2][64 * 64];   // V^T tile [d][key], cols XOR-swizzled by (d&7)
    __shared__ u16 lP[4][32][72];     // per-wave P [qrow][key], stride 72

    const int tid  = threadIdx.x;
    const int lane = tid & 63, w = tid >> 6;
    const int quad = lane >> 4, lm = lane & 15;

    const int idx  = blockIdx.x;
    const int half = idx >> 8;
    const int grp  = idx & 255;
    const int bh   = grp >> 3;
    const int j    = grp & 7;
    const int qt   = half ? j : 15 - j;
    const int h = bh & 15, b = bh >> 4;

    const int qb = qt * 128;
    const size_t headoff = (size_t)b * Tv * Cv + (size_t)h * Dv;
    const size_t vthead  = (size_t)h * 64 * Mv + (size_t)b * Tv;

    bf16x8 qf[2][2];
    #pragma unroll
    for (int nt = 0; nt < 2; nt++) {
        const u16* qptr = Qp + headoff + (size_t)(qb + w * 32 + nt * 16 + lm) * Cv + quad * 8;
        qf[0][nt] = *(const bf16x8*)(qptr);
        qf[1][nt] = *(const bf16x8*)(qptr + 32);
    }

    f32x4 zero = {0.f, 0.f, 0.f, 0.f};
    f32x4 oacc[2][4];
    #pragma unroll
    for (int mt = 0; mt < 2; mt++)
        #pragma unroll
        for (int nt = 0; nt < 4; nt++) oacc[mt][nt] = zero;
    float Lp[2] = {0.f, 0.f};

    const float SC = 0.18033688011112042f;
    const int rowi = lane >> 3, seg = lane & 7;
    const int niter = qt * 2 + 2;

    auto stage = [&](int bsel, int kt) {
        const int k0 = kt * 64;
        #pragma unroll
        for (int hf = 0; hf < 2; hf++) {
            int rbase = w * 16 + hf * 8;
            int row = rbase + rowi;
            int gseg = seg ^ (row & 7);
            gl_lds16(Kp + headoff + (size_t)(k0 + row) * Cv + gseg * 8, &lK[bsel][rbase * 64]);
            gl_lds16(VTg + vthead + (size_t)row * Mv + k0 + gseg * 8, &lVT[bsel][rbase * 64]);
        }
    };

    stage(0, 0);

    for (int kt = 0; kt < niter; kt++) {
        const int bsel = kt & 1;
        const int k0 = kt * 64;
        __syncthreads();
        if (kt + 1 < niter) stage(bsel ^ 1, kt + 1);

        f32x4 stt[4][2];
        #pragma unroll
        for (int mt = 0; mt < 4; mt++)
            #pragma unroll
            for (int nt = 0; nt < 2; nt++) stt[mt][nt] = zero;
        #pragma unroll
        for (int ks = 0; ks < 2; ks++) {
            #pragma unroll
            for (int mt = 0; mt < 4; mt++) {
                bf16x8 kf = *(const bf16x8*)
                    &lK[bsel][(mt * 16 + lm) * 64 + (((ks * 4 + quad) ^ (lm & 7)) * 8)];
                #pragma unroll
                for (int nt = 0; nt < 2; nt++)
                    stt[mt][nt] = MFMA16(kf, qf[ks][nt], stt[mt][nt]);
            }
        }

        const bool needmask = (kt >= niter - 2);
        #pragma unroll
        for (int mt = 0; mt < 4; mt++) {
            #pragma unroll
            for (int nt = 0; nt < 2; nt++) {
                const int keyb = k0 + mt * 16 + quad * 4;
                const int qrow = qb + w * 32 + nt * 16 + lm;
                ushort4 pk;
                float e0 = __builtin_amdgcn_exp2f(fmaf(stt[mt][nt][0], SC, -16.f));
                float e1 = __builtin_amdgcn_exp2f(fmaf(stt[mt][nt][1], SC, -16.f));
                float e2 = __builtin_amdgcn_exp2f(fmaf(stt[mt][nt][2], SC, -16.f));
                float e3 = __builtin_amdgcn_exp2f(fmaf(stt[mt][nt][3], SC, -16.f));
                if (needmask) {
                    if (keyb + 0 > qrow) e0 = 0.f;
                    if (keyb + 1 > qrow) e1 = 0.f;
                    if (keyb + 2 > qrow) e2 = 0.f;
                    if (keyb + 3 > qrow) e3 = 0.f;
                }
                Lp[nt] += e0 + e1 + e2 + e3;
                pk.x = (u16)(__float_as_uint(e0) >> 16);
                pk.y = (u16)(__float_as_uint(e1) >> 16);
                pk.z = (u16)(__float_as_uint(e2) >> 16);
                pk.w = (u16)(__float_as_uint(e3) >> 16);
                *(ushort4*)&lP[w][nt * 16 + lm][mt * 16 + quad * 4] = pk;
            }
        }

        #pragma unroll
        for (int ks = 0; ks < 2; ks++) {
            bf16x8 pf[2];
            #pragma unroll
            for (int mt = 0; mt < 2; mt++)
                pf[mt] = *(const bf16x8*)&lP[w][mt * 16 + lm][ks * 32 + quad * 8];
            #pragma unroll
            for (int nt = 0; nt < 4; nt++) {
                bf16x8 vf = *(const bf16x8*)
                    &lVT[bsel][(nt * 16 + lm) * 64 + (((ks * 4 + quad) ^ (lm & 7)) * 8)];
                #pragma unroll
                for (int mt = 0; mt < 2; mt++)
                    oacc[mt][nt] = MFMA16(pf[mt], vf, oacc[mt][nt]);
            }
        }
    }

    float Lred[2];
    #pragma unroll
    for (int nt = 0; nt < 2; nt++) {
        float L = Lp[nt];
        L += __shfl_xor(L, 16, 64);
        L += __shfl_xor(L, 32, 64);
        Lred[nt] = 1.0f / L;
    }
    #pragma unroll
    for (int mt = 0; mt < 2; mt++) {
        float inv[4];
        #pragma unroll
        for (int r = 0; r < 4; r++)
            inv[r] = __shfl(Lred[mt], (lane & 48) | (quad * 4 + r), 64);
        #pragma unroll
        for (int nt = 0; nt < 4; nt++) {
            #pragma unroll
            for (int r = 0; r < 4; r++) {
                int row = qb + w * 32 + mt * 16 + quad * 4 + r;
                Op[headoff + (size_t)row * Cv + nt * 16 + lm] = f2bf(oacc[mt][nt][r] * inv[r]);
            }
        }
    }
}

// ---------------- launcher ----------------
extern "C" void kernel_launch(void* const* d_in, const int* in_sizes, int n_in,
                              void* d_out, int out_size, void* d_ws, size_t ws_size,
                              hipStream_t stream) {
    const float* x  = (const float*)d_in[0];
    const float* Wq = (const float*)d_in[1];
    const float* bq = (const float*)d_in[2];
    const float* Wk = (const float*)d_in[3];
    const float* bk = (const float*)d_in[4];
    const float* Wv = (const float*)d_in[5];
    const float* bv = (const float*)d_in[6];
    const float* Wo = (const float*)d_in[7];
    const float* bo = (const float*)d_in[8];
    u16* ws = (u16*)d_ws;

    convert_all<<<8192, 256, 0, stream>>>(x, Wq, Wk, Wv, Wo, ws);

    gemm_qkv<<<dim3(24, 32), 256, 0, stream>>>(
        ws + OFF_XB, ws + OFF_WQ, ws + OFF_WK, ws + OFF_WV,
        bq, bk, bv, ws + OFF_Q, ws + OFF_K, ws + OFF_VT);

    attn<<<512, 256, 0, stream>>>(ws + OFF_Q, ws + OFF_K, ws + OFF_VT, ws + OFF_A);

    gemm_o64<<<dim3(16, 32), 256, 0, stream>>>(ws + OFF_A, ws + OFF_WO, bo, (float*)d_out);
}

// Round 6
// 182.074 us; speedup vs baseline: 1.2540x; 1.0787x over previous
//
#include <hip/hip_runtime.h>

typedef unsigned short u16;
typedef __attribute__((ext_vector_type(8))) __bf16 bf16x8;
typedef __attribute__((ext_vector_type(4))) float f32x4;
typedef __attribute__((ext_vector_type(4))) unsigned int u32x4;

#define MFMA16(a, b, c) __builtin_amdgcn_mfma_f32_16x16x32_bf16(a, b, c, 0, 0, 0)

__device__ __forceinline__ u16 f2bf(float f) {
    unsigned u = __float_as_uint(f);
    u = (u + 0x7FFFu + ((u >> 16) & 1u)) >> 16;
    return (u16)u;
}

// async global->LDS, 16B per lane; LDS dest = wave-uniform base + lane*16
__device__ __forceinline__ void gl_lds16(const u16* g, u16* l) {
    __builtin_amdgcn_global_load_lds(
        (const __attribute__((address_space(1))) unsigned int*)g,
        (__attribute__((address_space(3))) unsigned int*)l, 16, 0, 0);
}

static constexpr int Bv = 2, Tv = 2048, Cv = 1024, Hv = 16, Dv = 64;
static constexpr int Mv = Bv * Tv; // 4096

// ws element offsets (u16 elements)
static constexpr size_t OFF_XB = 0;                      // x bf16       [4096,1024]
static constexpr size_t OFF_WQ = 4194304;                // Wq bf16      [1024,1024]
static constexpr size_t OFF_WK = OFF_WQ + 1048576;
static constexpr size_t OFF_WV = OFF_WK + 1048576;
static constexpr size_t OFF_WO = OFF_WV + 1048576;
static constexpr size_t OFF_Q  = OFF_WO + 1048576;       // Q bf16 [M, C]
static constexpr size_t OFF_K  = OFF_Q + 4194304;        // K bf16 [M, C]
static constexpr size_t OFF_VT = OFF_K + 4194304;        // V^T bf16 [C, M]
static constexpr size_t OFF_A  = OFF_VT + 4194304;       // attended bf16 [M, C]

// ---------------- fp32 -> bf16 convert (x + 4 weights) ----------------
__global__ __launch_bounds__(256) void convert_all(
    const float* __restrict__ x,
    const float* __restrict__ wq, const float* __restrict__ wk,
    const float* __restrict__ wv, const float* __restrict__ wo,
    u16* __restrict__ dst)
{
    int i4 = blockIdx.x * blockDim.x + threadIdx.x;
    if (i4 >= 2097152) return;
    int idx = i4 * 4;
    const float* src; int off;
    if (idx < 4194304) { src = x; off = idx; }
    else {
        int rel = idx - 4194304;
        int j = rel >> 20;
        off = rel & 1048575;
        src = (j == 0) ? wq : (j == 1) ? wk : (j == 2) ? wv : wo;
    }
    float4 v = *(const float4*)(src + off);
    ushort4 o;
    o.x = f2bf(v.x); o.y = f2bf(v.y); o.z = f2bf(v.z); o.w = f2bf(v.w);
    *(ushort4*)(dst + idx) = o;
}

// ---------------- 128x128-tile bf16 GEMM, BK=64, XOR-swizzled LDS ----------------
template <bool OUT_BF16, bool ROWBIAS>
__device__ __forceinline__ void gemm128_b64(
    const u16* __restrict__ A, const u16* __restrict__ Wt,
    const float* __restrict__ bias, void* __restrict__ outp,
    int m0, int n0, int N, int K)
{
    __shared__ u16 lA[128 * 64];   // [row][64], cols XOR-swizzled by (row&7)
    __shared__ u16 lB[128 * 64];
    const int tid  = threadIdx.x;
    const int lane = tid & 63, w = tid >> 6;
    const int quad = lane >> 4, lm = lane & 15;
    const int wm = (w & 1) * 64, wn = (w >> 1) * 64;

    f32x4 zero = {0.f, 0.f, 0.f, 0.f};
    f32x4 acc[4][4];
    #pragma unroll
    for (int mt = 0; mt < 4; mt++)
        #pragma unroll
        for (int nt = 0; nt < 4; nt++) acc[mt][nt] = zero;

    const int rowi = lane >> 3, seg = lane & 7;

    for (int k0 = 0; k0 < K; k0 += 64) {
        #pragma unroll
        for (int i = 0; i < 4; i++) {
            int rbase = w * 32 + i * 8;
            int row = rbase + rowi;
            int gseg = seg ^ (row & 7);
            gl_lds16(A  + (size_t)(m0 + row) * K + k0 + gseg * 8, &lA[rbase * 64]);
            gl_lds16(Wt + (size_t)(n0 + row) * K + k0 + gseg * 8, &lB[rbase * 64]);
        }
        __syncthreads();
        #pragma unroll
        for (int ks = 0; ks < 2; ks++) {
            const int swz = ((ks * 4 + quad) ^ (lm & 7)) * 8;
            bf16x8 af[4], bf[4];
            #pragma unroll
            for (int mt = 0; mt < 4; mt++)
                af[mt] = *(const bf16x8*)&lA[(wm + mt * 16 + lm) * 64 + swz];
            #pragma unroll
            for (int nt = 0; nt < 4; nt++)
                bf[nt] = *(const bf16x8*)&lB[(wn + nt * 16 + lm) * 64 + swz];
            #pragma unroll
            for (int mt = 0; mt < 4; mt++)
                #pragma unroll
                for (int nt = 0; nt < 4; nt++)
                    acc[mt][nt] = MFMA16(af[mt], bf[nt], acc[mt][nt]);
        }
        __syncthreads();
    }

    #pragma unroll
    for (int nt = 0; nt < 4; nt++) {
        int col = n0 + wn + nt * 16 + lm;
        float cb = ROWBIAS ? 0.f : bias[col];
        #pragma unroll
        for (int mt = 0; mt < 4; mt++) {
            #pragma unroll
            for (int r = 0; r < 4; r++) {
                int row = m0 + wm + mt * 16 + quad * 4 + r;
                float v = acc[mt][nt][r] + (ROWBIAS ? bias[row] : cb);
                if (OUT_BF16) ((u16*)outp)[(size_t)row * N + col] = f2bf(v);
                else          ((float*)outp)[(size_t)row * N + col] = v;
            }
        }
    }
}

// fused QKV: grid (24, 32).
__global__ __launch_bounds__(256) void gemm_qkv(
    const u16* __restrict__ A,
    const u16* __restrict__ Wq, const u16* __restrict__ Wk, const u16* __restrict__ Wv,
    const float* __restrict__ bq, const float* __restrict__ bk, const float* __restrict__ bv,
    u16* __restrict__ Q, u16* __restrict__ K, u16* __restrict__ VT)
{
    int nb = blockIdx.x;
    int which = nb >> 3;
    if (which == 0) {
        gemm128_b64<true, false>(A, Wq, bq, Q, blockIdx.y * 128, (nb & 7) * 128, Cv, Cv);
    } else if (which == 1) {
        gemm128_b64<true, false>(A, Wk, bk, K, blockIdx.y * 128, (nb & 7) * 128, Cv, Cv);
    } else {
        // V^T: rows = channel (M'=1024), cols = token (N'=4096); A'=Wv, B'=x; bias by row
        gemm128_b64<true, true>(Wv, A, bv, VT, (nb & 7) * 128, blockIdx.y * 128, Mv, Cv);
    }
}

// output proj: 128x64 tiles, BK=64, grid (16, 32)
__global__ __launch_bounds__(256) void gemm_o64(
    const u16* __restrict__ A, const u16* __restrict__ Wt,
    const float* __restrict__ bias, float* __restrict__ outp)
{
    __shared__ u16 lA[128 * 64];
    __shared__ u16 lB[64 * 64];
    const int tid  = threadIdx.x;
    const int lane = tid & 63, w = tid >> 6;
    const int quad = lane >> 4, lm = lane & 15;
    const int m0 = blockIdx.y * 128, n0 = blockIdx.x * 64;
    const int K = Cv;

    f32x4 zero = {0.f, 0.f, 0.f, 0.f};
    f32x4 acc[2][4];
    #pragma unroll
    for (int mt = 0; mt < 2; mt++)
        #pragma unroll
        for (int nt = 0; nt < 4; nt++) acc[mt][nt] = zero;

    const int rowi = lane >> 3, seg = lane & 7;

    for (int k0 = 0; k0 < K; k0 += 64) {
        #pragma unroll
        for (int i = 0; i < 4; i++) {
            int rbase = w * 32 + i * 8;
            int row = rbase + rowi;
            int gseg = seg ^ (row & 7);
            gl_lds16(A + (size_t)(m0 + row) * K + k0 + gseg * 8, &lA[rbase * 64]);
        }
        {
            int rbase = w * 16, row0 = rbase + rowi, row1 = row0 + 8;
            gl_lds16(Wt + (size_t)(n0 + row0) * K + k0 + (seg ^ (row0 & 7)) * 8, &lB[rbase * 64]);
            gl_lds16(Wt + (size_t)(n0 + row1) * K + k0 + (seg ^ (row1 & 7)) * 8, &lB[(rbase + 8) * 64]);
        }
        __syncthreads();
        #pragma unroll
        for (int ks = 0; ks < 2; ks++) {
            const int swz = ((ks * 4 + quad) ^ (lm & 7)) * 8;
            bf16x8 af[2], bf[4];
            #pragma unroll
            for (int mt = 0; mt < 2; mt++)
                af[mt] = *(const bf16x8*)&lA[(w * 32 + mt * 16 + lm) * 64 + swz];
            #pragma unroll
            for (int nt = 0; nt < 4; nt++)
                bf[nt] = *(const bf16x8*)&lB[(nt * 16 + lm) * 64 + swz];
            #pragma unroll
            for (int mt = 0; mt < 2; mt++)
                #pragma unroll
                for (int nt = 0; nt < 4; nt++)
                    acc[mt][nt] = MFMA16(af[mt], bf[nt], acc[mt][nt]);
        }
        __syncthreads();
    }

    #pragma unroll
    for (int nt = 0; nt < 4; nt++) {
        int col = n0 + nt * 16 + lm;
        float bvv = bias[col];
        #pragma unroll
        for (int mt = 0; mt < 2; mt++) {
            #pragma unroll
            for (int r = 0; r < 4; r++) {
                int row = m0 + w * 32 + mt * 16 + quad * 4 + r;
                outp[(size_t)row * Cv + col] = acc[mt][nt][r] + bvv;
            }
        }
    }
}

// ---------------- flash attention v5: key-split wave-groups ----------------
// 512 blocks x 512 thr. Block = (bh, qt): 128 q-rows. 8 waves = 2 groups of 4;
// group g handles 64-key tiles kt = 2i+g, i in [0, qt+1) -- exactly even split.
// Fixed-exponent softmax => partial (O, L) over disjoint keys simply ADD.
__global__ __launch_bounds__(512) void attn(
    const u16* __restrict__ Qp, const u16* __restrict__ Kp,
    const u16* __restrict__ VTg, u16* __restrict__ Op)
{
    __shared__ u16 lK[2][64 * 64];    // per-group K-tile [key][d], cols XOR-swizzled
    __shared__ u16 lVT[2][64 * 64];   // per-group V^T tile [d][key], cols XOR-swizzled
    __shared__ u16 lP[8][32][72];     // per-wave P; reused as f32 merge buffer after loop

    const int tid  = threadIdx.x;
    const int lane = tid & 63, w = tid >> 6;     // w 0..7
    const int g = w >> 2, wl = w & 3;            // group, wave-in-group
    const int quad = lane >> 4, lm = lane & 15;

    const int idx  = blockIdx.x;
    const int half = idx >> 8;
    const int grp  = idx & 255;
    const int bh   = (half << 4) | (grp >> 4);   // pairs (idx, idx+256): diff bh, compl. qt
    const int j    = grp & 15;
    const int qt   = half ? j : 15 - j;
    const int h = bh & 15, b = bh >> 4;

    const int qb = qt * 128;
    const size_t headoff = (size_t)b * Tv * Cv + (size_t)h * Dv;
    const size_t vthead  = (size_t)h * 64 * Mv + (size_t)b * Tv;

    // Q frags (both groups load the same rows: wl*32 .. wl*32+32)
    bf16x8 qf[2][2];
    #pragma unroll
    for (int nt = 0; nt < 2; nt++) {
        const u16* qptr = Qp + headoff + (size_t)(qb + wl * 32 + nt * 16 + lm) * Cv + quad * 8;
        qf[0][nt] = *(const bf16x8*)(qptr);
        qf[1][nt] = *(const bf16x8*)(qptr + 32);
    }

    f32x4 zero = {0.f, 0.f, 0.f, 0.f};
    f32x4 oacc[2][4];
    #pragma unroll
    for (int mt = 0; mt < 2; mt++)
        #pragma unroll
        for (int nt = 0; nt < 4; nt++) oacc[mt][nt] = zero;
    float Lp[2] = {0.f, 0.f};

    const float SC = 0.18033688011112042f;  // (1/sqrt(64)) * log2(e)
    const int rowi = lane >> 3, seg = lane & 7;

    auto stage = [&](int kt) {
        const int k0 = kt * 64;
        #pragma unroll
        for (int hf = 0; hf < 2; hf++) {
            int rbase = wl * 16 + hf * 8;
            int row = rbase + rowi;
            int gseg = seg ^ (row & 7);
            gl_lds16(Kp + headoff + (size_t)(k0 + row) * Cv + gseg * 8, &lK[g][rbase * 64]);
            gl_lds16(VTg + vthead + (size_t)row * Mv + k0 + gseg * 8, &lVT[g][rbase * 64]);
        }
    };

    auto body = [&](int kt, bool domask) __attribute__((always_inline)) {
        const int k0 = kt * 64;
        // S^T = K Q^T
        f32x4 stt[4][2];
        #pragma unroll
        for (int mt = 0; mt < 4; mt++)
            #pragma unroll
            for (int nt = 0; nt < 2; nt++) stt[mt][nt] = zero;
        #pragma unroll
        for (int ks = 0; ks < 2; ks++) {
            #pragma unroll
            for (int mt = 0; mt < 4; mt++) {
                bf16x8 kf = *(const bf16x8*)
                    &lK[g][(mt * 16 + lm) * 64 + (((ks * 4 + quad) ^ (lm & 7)) * 8)];
                #pragma unroll
                for (int nt = 0; nt < 2; nt++)
                    stt[mt][nt] = MFMA16(kf, qf[ks][nt], stt[mt][nt]);
            }
        }
        // softmax (fixed exponent), pack to lP
        #pragma unroll
        for (int mt = 0; mt < 4; mt++) {
            #pragma unroll
            for (int nt = 0; nt < 2; nt++) {
                const int keyb = k0 + mt * 16 + quad * 4;
                const int qrow = qb + wl * 32 + nt * 16 + lm;
                float e0 = __builtin_amdgcn_exp2f(fmaf(stt[mt][nt][0], SC, -16.f));
                float e1 = __builtin_amdgcn_exp2f(fmaf(stt[mt][nt][1], SC, -16.f));
                float e2 = __builtin_amdgcn_exp2f(fmaf(stt[mt][nt][2], SC, -16.f));
                float e3 = __builtin_amdgcn_exp2f(fmaf(stt[mt][nt][3], SC, -16.f));
                if (domask) {
                    if (keyb + 0 > qrow) e0 = 0.f;
                    if (keyb + 1 > qrow) e1 = 0.f;
                    if (keyb + 2 > qrow) e2 = 0.f;
                    if (keyb + 3 > qrow) e3 = 0.f;
                }
                Lp[nt] += e0 + e1 + e2 + e3;
                ushort4 pk;
                pk.x = (u16)(__float_as_uint(e0) >> 16);
                pk.y = (u16)(__float_as_uint(e1) >> 16);
                pk.z = (u16)(__float_as_uint(e2) >> 16);
                pk.w = (u16)(__float_as_uint(e3) >> 16);
                *(ushort4*)&lP[w][nt * 16 + lm][mt * 16 + quad * 4] = pk;
            }
        }
        // O += P V
        #pragma unroll
        for (int ks = 0; ks < 2; ks++) {
            bf16x8 pf[2];
            #pragma unroll
            for (int mt = 0; mt < 2; mt++)
                pf[mt] = *(const bf16x8*)&lP[w][mt * 16 + lm][ks * 32 + quad * 8];
            #pragma unroll
            for (int nt = 0; nt < 4; nt++) {
                bf16x8 vf = *(const bf16x8*)
                    &lVT[g][(nt * 16 + lm) * 64 + (((ks * 4 + quad) ^ (lm & 7)) * 8)];
                #pragma unroll
                for (int mt = 0; mt < 2; mt++)
                    oacc[mt][nt] = MFMA16(pf[mt], vf, oacc[mt][nt]);
            }
        }
    };

    // main loop: group g's tile i is kt = 2i+g; last iter (i==qt) needs masking
    for (int i = 0; i < qt; i++) {
        if (i) __syncthreads();        // prior compute done before overwrite
        stage(2 * i + g);
        __syncthreads();               // staging visible
        body(2 * i + g, false);
    }
    if (qt) __syncthreads();
    stage(2 * qt + g);
    __syncthreads();
    body(2 * qt + g, true);
    __syncthreads();                   // lP reads done before merge reuses it

    // ---- merge group partials through LDS (reuse lP as f32 buffer) ----
    float* lO = (float*)&lP[0][0][0];            // [32 slots][256 lanes]
    float* lL = lO + 32 * 256;                   // [2][256]
    const int t = tid & 255;
    if (g == 1) {
        #pragma unroll
        for (int mt = 0; mt < 2; mt++)
            #pragma unroll
            for (int nt = 0; nt < 4; nt++)
                #pragma unroll
                for (int r = 0; r < 4; r++)
                    lO[(mt * 16 + nt * 4 + r) * 256 + t] = oacc[mt][nt][r];
        lL[t] = Lp[0];
        lL[256 + t] = Lp[1];
    }
    __syncthreads();
    if (g == 0) {
        #pragma unroll
        for (int mt = 0; mt < 2; mt++)
            #pragma unroll
            for (int nt = 0; nt < 4; nt++)
                #pragma unroll
                for (int r = 0; r < 4; r++)
                    oacc[mt][nt][r] += lO[(mt * 16 + nt * 4 + r) * 256 + t];
        Lp[0] += lL[t];
        Lp[1] += lL[256 + t];

        float Lred[2];
        #pragma unroll
        for (int nt = 0; nt < 2; nt++) {
            float L = Lp[nt];
            L += __shfl_xor(L, 16, 64);
            L += __shfl_xor(L, 32, 64);
            Lred[nt] = 1.0f / L;
        }
        #pragma unroll
        for (int mt = 0; mt < 2; mt++) {
            float inv[4];
            #pragma unroll
            for (int r = 0; r < 4; r++)
                inv[r] = __shfl(Lred[mt], (lane & 48) | (quad * 4 + r), 64);
            #pragma unroll
            for (int nt = 0; nt < 4; nt++) {
                #pragma unroll
                for (int r = 0; r < 4; r++) {
                    int row = qb + wl * 32 + mt * 16 + quad * 4 + r;
                    Op[headoff + (size_t)row * Cv + nt * 16 + lm] = f2bf(oacc[mt][nt][r] * inv[r]);
                }
            }
        }
    }
}

// ---------------- launcher ----------------
extern "C" void kernel_launch(void* const* d_in, const int* in_sizes, int n_in,
                              void* d_out, int out_size, void* d_ws, size_t ws_size,
                              hipStream_t stream) {
    const float* x  = (const float*)d_in[0];
    const float* Wq = (const float*)d_in[1];
    const float* bq = (const float*)d_in[2];
    const float* Wk = (const float*)d_in[3];
    const float* bk = (const float*)d_in[4];
    const float* Wv = (const float*)d_in[5];
    const float* bv = (const float*)d_in[6];
    const float* Wo = (const float*)d_in[7];
    const float* bo = (const float*)d_in[8];
    u16* ws = (u16*)d_ws;

    convert_all<<<8192, 256, 0, stream>>>(x, Wq, Wk, Wv, Wo, ws);

    gemm_qkv<<<dim3(24, 32), 256, 0, stream>>>(
        ws + OFF_XB, ws + OFF_WQ, ws + OFF_WK, ws + OFF_WV,
        bq, bk, bv, ws + OFF_Q, ws + OFF_K, ws + OFF_VT);

    attn<<<512, 512, 0, stream>>>(ws + OFF_Q, ws + OFF_K, ws + OFF_VT, ws + OFF_A);

    gemm_o64<<<dim3(16, 32), 256, 0, stream>>>(ws + OFF_A, ws + OFF_WO, bo, (float*)d_out);
}